// Round 5
// baseline (143.688 us; speedup 1.0000x reference)
//
#include <hip/hip_runtime.h>
#include <hip/hip_fp16.h>
#include <stdint.h>

#define IN_F 8192
#define OUT_F 8192
#define NGROUPS 64
#define QW_COLS 1024   // IN_F/8 packed int32 per output row
#define QZ_COLS 8
#define M_TOTAL 128
#define BN 128
#define BK 128         // == GROUP_SIZE
#define KSPLIT 8
#define KRANGE (IN_F / KSPLIT)  // 1024
#define NITER (KRANGE / BK)     // 8
#define NTILES (OUT_F / BN)     // 64

typedef _Float16 half8 __attribute__((ext_vector_type(8)));
typedef float floatx16 __attribute__((ext_vector_type(16)));

#define LSTRIDE 136  // 128 + 8 pad halves; stride 68 dwords == 4 mod 32 -> uniform banks

// exact dequant: fma rounds once in f32, then once to f16 == reference.
__device__ inline uint16_t dq16(uint32_t q, float sf, float nzs) {
  float fw = fmaf((float)q, sf, nzs);
  __half h = __float2half(fw);
  return __builtin_bit_cast(uint16_t, h);
}

__device__ inline half8 lda_f16(const uint16_t* p) { return *(const half8*)p; }

// XF16=1: A-frags direct from pre-converted f16 x in ws (L2-resident).
// XF16=0: A-frags from f32 x with on-the-fly convert (fallback, no ws needed).
template <int XF16>
__global__ __launch_bounds__(256) void awq_main(
    const float* __restrict__ xf32, const uint16_t* __restrict__ xf16,
    const int* __restrict__ qweight, const float* __restrict__ scales,
    const int* __restrict__ qzeros, float* __restrict__ out) {
  __shared__ uint16_t wsl[BN * LSTRIDE];  // 34816 B (weights only; x never staged)

  const int tid = threadIdx.x;
  const int bx = blockIdx.x;
  const int ntile = bx & (NTILES - 1);
  const int kslice = bx >> 6;
  const int n0 = ntile * BN;
  const int kbase = kslice * KRANGE;

  const int lane = tid & 63;
  const int wave = tid >> 6;
  const int mw = wave >> 1;   // 2 m-waves x 2 n-waves; wave tile 64x64
  const int nw = wave & 1;
  const int l31 = lane & 31;
  const int half = lane >> 5;

  floatx16 acc[2][2] = {};

  // dequant map: 2048 words = 128 cols x 16; thread -> col=tid>>1, 8 words
  const int wcol = tid >> 1;
  const int wh = tid & 1;
  const long long qw_base = (long long)(n0 + wcol) * QW_COLS + (kbase >> 3) + wh * 8;
  const long long sc_base = (long long)(n0 + wcol) * NGROUPS;
  const long long qz_base = (long long)(n0 + wcol) * QZ_COLS;

  // A-operand row pointers (per-lane): m = mw*64 + im*32 + l31, k-offset half*8
  const long long arow0 = (long long)(mw * 64 + l31) * IN_F + half * 8;
  const long long arow1 = (long long)(mw * 64 + 32 + l31) * IN_F + half * 8;

  // B pointer base in LDS
  const uint16_t* bbase = &wsl[(nw * 64 + l31) * LSTRIDE + half * 8];

  // preload qweight words for it=0
  uint4 q0 = *(const uint4*)(qweight + qw_base);
  uint4 q1 = *(const uint4*)(qweight + qw_base + 4);

  for (int it = 0; it < NITER; ++it) {
    const int g = kslice * NITER + it;  // group index == (kbase + it*BK)/128

    // ---- dequant this iter's 8 words (64 nibbles) into regs
    const float sf = scales[sc_base + g];
    const int zw = qzeros[qz_base + (g >> 3)];
    const float zf = (float)((uint32_t)(zw >> ((g & 7) * 4)) & 0xFu);
    const float nzs = -zf * sf;
    union { uint16_t h[64]; uint4 v[8]; } r;
    {
      const uint32_t w[8] = {q0.x, q0.y, q0.z, q0.w, q1.x, q1.y, q1.z, q1.w};
#pragma unroll
      for (int wi = 0; wi < 8; ++wi)
#pragma unroll
        for (int j = 0; j < 8; ++j)
          r.h[wi * 8 + j] = dq16((w[wi] >> (4 * j)) & 15u, sf, nzs);
    }

    if (it > 0) __syncthreads();  // prior MFMA readers done before overwrite

    {
      uint4* dst = (uint4*)(&wsl[wcol * LSTRIDE + wh * 64]);
#pragma unroll
      for (int c = 0; c < 8; ++c) dst[c] = r.v[c];
    }
    __syncthreads();

    // ---- prefetch next iter's qweight (drains under the MFMA phase)
    if (it + 1 < NITER) {
      q0 = *(const uint4*)(qweight + qw_base + (it + 1) * 16);
      q1 = *(const uint4*)(qweight + qw_base + (it + 1) * 16 + 4);
    }

    // ---- MFMA phase: 8 k16-steps; A direct from global, B from LDS
    const int kglob = kbase + it * BK;
#pragma unroll
    for (int ks = 0; ks < 8; ++ks) {
      const int ko = kglob + ks * 16;
      half8 a0, a1;
      if (XF16) {
        a0 = lda_f16(xf16 + arow0 + ko);
        a1 = lda_f16(xf16 + arow1 + ko);
      } else {
        float4 f0 = *(const float4*)(xf32 + arow0 + ko);
        float4 f1 = *(const float4*)(xf32 + arow0 + ko + 4);
        a0 = half8{(_Float16)f0.x, (_Float16)f0.y, (_Float16)f0.z, (_Float16)f0.w,
                   (_Float16)f1.x, (_Float16)f1.y, (_Float16)f1.z, (_Float16)f1.w};
        float4 g0 = *(const float4*)(xf32 + arow1 + ko);
        float4 g1 = *(const float4*)(xf32 + arow1 + ko + 4);
        a1 = half8{(_Float16)g0.x, (_Float16)g0.y, (_Float16)g0.z, (_Float16)g0.w,
                   (_Float16)g1.x, (_Float16)g1.y, (_Float16)g1.z, (_Float16)g1.w};
      }
      half8 b0 = *(const half8*)(bbase + ks * 16);
      half8 b1 = *(const half8*)(bbase + 32 * LSTRIDE + ks * 16);
      acc[0][0] = __builtin_amdgcn_mfma_f32_32x32x16_f16(a0, b0, acc[0][0], 0, 0, 0);
      acc[0][1] = __builtin_amdgcn_mfma_f32_32x32x16_f16(a0, b1, acc[0][1], 0, 0, 0);
      acc[1][0] = __builtin_amdgcn_mfma_f32_32x32x16_f16(a1, b0, acc[1][0], 0, 0, 0);
      acc[1][1] = __builtin_amdgcn_mfma_f32_32x32x16_f16(a1, b1, acc[1][1], 0, 0, 0);
    }
  }

  // ---- epilogue: K-split partials into bias-pre-initialized out
  // C/D 32x32: col = lane&31, row = (reg&3) + 8*(reg>>2) + 4*(lane>>5)
  const int cn = n0 + nw * 64 + l31;
#pragma unroll
  for (int im = 0; im < 2; ++im) {
#pragma unroll
    for (int in2 = 0; in2 < 2; ++in2) {
#pragma unroll
      for (int reg = 0; reg < 16; ++reg) {
        int m = mw * 64 + im * 32 + (reg & 3) + 8 * (reg >> 2) + 4 * half;
        atomicAdd(out + (long long)m * OUT_F + cn + in2 * 32, acc[im][in2][reg]);
      }
    }
  }
}

// fused prologue: out = bias (broadcast rows) and ws = f16(x).
__global__ __launch_bounds__(256) void prologue(
    const float* __restrict__ x, const float* __restrict__ bias,
    float* __restrict__ out, uint16_t* __restrict__ xf16) {
  int idx = (blockIdx.x * 256 + threadIdx.x) * 8;
  float4 b0 = *(const float4*)(bias + (idx & (OUT_F - 1)));
  float4 b1 = *(const float4*)(bias + ((idx + 4) & (OUT_F - 1)));
  *(float4*)(out + idx) = b0;
  *(float4*)(out + idx + 4) = b1;
  float4 v0 = *(const float4*)(x + idx);
  float4 v1 = *(const float4*)(x + idx + 4);
  union { uint16_t h[8]; uint4 v; } r;
  r.h[0] = __builtin_bit_cast(uint16_t, __float2half(v0.x));
  r.h[1] = __builtin_bit_cast(uint16_t, __float2half(v0.y));
  r.h[2] = __builtin_bit_cast(uint16_t, __float2half(v0.z));
  r.h[3] = __builtin_bit_cast(uint16_t, __float2half(v0.w));
  r.h[4] = __builtin_bit_cast(uint16_t, __float2half(v1.x));
  r.h[5] = __builtin_bit_cast(uint16_t, __float2half(v1.y));
  r.h[6] = __builtin_bit_cast(uint16_t, __float2half(v1.z));
  r.h[7] = __builtin_bit_cast(uint16_t, __float2half(v1.w));
  *(uint4*)(xf16 + idx) = r.v;
}

__global__ __launch_bounds__(256) void init_out(const float* __restrict__ bias,
                                                float* __restrict__ out) {
  int idx = (blockIdx.x * 256 + threadIdx.x) * 4;
  float4 b = *(const float4*)(bias + (idx & (OUT_F - 1)));
  *(float4*)(out + idx) = b;
}

extern "C" void kernel_launch(void* const* d_in, const int* in_sizes, int n_in,
                              void* d_out, int out_size, void* d_ws, size_t ws_size,
                              hipStream_t stream) {
  const float* x = (const float*)d_in[0];
  const int* qw = (const int*)d_in[1];
  const float* sc = (const float*)d_in[2];
  const int* qz = (const int*)d_in[3];
  const float* bias = (const float*)d_in[4];
  float* out = (float*)d_out;
  uint16_t* xf16 = (uint16_t*)d_ws;

  const size_t need = (size_t)M_TOTAL * IN_F * sizeof(uint16_t);  // 2 MiB
  if (ws_size >= need) {
    prologue<<<(M_TOTAL * IN_F) / (256 * 8), 256, 0, stream>>>(x, bias, out, xf16);
    awq_main<1><<<NTILES * KSPLIT, 256, 0, stream>>>(x, xf16, qw, sc, qz, out);
  } else {
    init_out<<<(M_TOTAL * OUT_F) / (256 * 4), 256, 0, stream>>>(bias, out);
    awq_main<0><<<NTILES * KSPLIT, 256, 0, stream>>>(x, xf16, qw, sc, qz, out);
  }
}

// Round 6
// 129.755 us; speedup vs baseline: 1.1074x; 1.1074x over previous
//
#include <hip/hip_runtime.h>
#include <hip/hip_fp16.h>
#include <stdint.h>

#define IN_F 8192
#define OUT_F 8192
#define NGROUPS 64
#define QW_COLS 1024   // IN_F/8 packed int32 per output row
#define QZ_COLS 8
#define M_TOTAL 128
#define BN 128
#define BK 128         // == GROUP_SIZE
#define KSPLIT 8
#define KRANGE (IN_F / KSPLIT)  // 1024
#define NITER (KRANGE / BK)     // 8
#define NTILES (OUT_F / BN)     // 64
#define K16S (IN_F / 16)        // 512 k16-steps total

typedef _Float16 half8 __attribute__((ext_vector_type(8)));
typedef float floatx16 __attribute__((ext_vector_type(16)));

// Dequant one packed word (8 nibbles) -> 8 f16 in order, bit-identical to ref:
// t_p = (1024+q_p, 1024+q_{p+4}); pk_sub (1024+z)-pair is exact int; pk_mul
// by (s,s) rounds once == ref's exact-f32-product -> f16 single rounding.
__device__ inline uint4 dq_word(uint32_t w, uint32_t hz2u, uint32_t s2u) {
  const __half2 hz2 = __builtin_bit_cast(__half2, hz2u);
  const __half2 s2 = __builtin_bit_cast(__half2, s2u);
  uint32_t r[4];
#pragma unroll
  for (int p = 0; p < 4; ++p) {
    uint32_t t = ((w >> (4 * p)) & 0x000F000Fu) | 0x64006400u;
    __half2 v = __hmul2(__hsub2(__builtin_bit_cast(__half2, t), hz2), s2);
    r[p] = __builtin_bit_cast(uint32_t, v);  // (elem p, elem p+4)
  }
  uint4 o;
  o.x = (r[0] & 0xFFFFu) | (r[1] << 16);          // h0,h1
  o.y = (r[2] & 0xFFFFu) | (r[3] << 16);          // h2,h3
  o.z = (r[0] >> 16) | (r[1] & 0xFFFF0000u);      // h4,h5
  o.w = (r[2] >> 16) | (r[3] & 0xFFFF0000u);      // h6,h7
  return o;
}

// XF16=1: A from fragment-major pre-swizzled f16 in ws -> coalesced 1KB loads.
// XF16=0: fallback, scattered f32 loads (correct, slow).
template <int XF16>
__global__ __launch_bounds__(256) void awq_main(
    const float* __restrict__ xf32, const uint16_t* __restrict__ aT,
    const int* __restrict__ qweight, const float* __restrict__ scales,
    const int* __restrict__ qzeros, float* __restrict__ out) {
  // B tile in MFMA-fragment-major order: bT[nblk(4)][ks(8)][lane(64)][8]
  __shared__ uint16_t bT[BN * BK];  // 32 KiB

  const int tid = threadIdx.x;
  const int bx = blockIdx.x;
  const int ntile = bx & (NTILES - 1);  // ntile%8 == bx%8 -> per-XCD qweight slice
  const int kslice = bx >> 6;
  const int n0 = ntile * BN;
  const int kbase = kslice * KRANGE;

  const int lane = tid & 63;
  const int wave = tid >> 6;
  const int mw = wave >> 1;   // 2 m-waves x 2 n-waves; wave tile 64x64
  const int nw = wave & 1;
  const int l31 = lane & 31;
  const int half = lane >> 5;

  floatx16 acc[2][2] = {};

  // dequant map: 128 cols x 16 words per iter; thread -> (col, k-half), 8 words
  const int wcol = tid >> 1;
  const int wh = tid & 1;
  const int nblk_w = wcol >> 5;
  const int l31_w = wcol & 31;
  const long long qw_base = (long long)(n0 + wcol) * QW_COLS + (kbase >> 3) + wh * 8;
  const long long sc_base = (long long)(n0 + wcol) * NGROUPS;
  const long long qz_base = (long long)(n0 + wcol) * QZ_COLS;
  uint16_t* bdst0 = &bT[((nblk_w * 8 + wh * 4) * 64 + l31_w) * 8];

  // fallback A row pointers
  const long long arow0 = (long long)(mw * 64 + l31) * IN_F + half * 8;
  const long long arow1 = (long long)(mw * 64 + 32 + l31) * IN_F + half * 8;

  uint4 q0 = *(const uint4*)(qweight + qw_base);
  uint4 q1 = *(const uint4*)(qweight + qw_base + 4);

  for (int it = 0; it < NITER; ++it) {
    const int g = kslice * NITER + it;

    const float sf = scales[sc_base + g];
    const int zw = qzeros[qz_base + (g >> 3)];
    const uint32_t z = (uint32_t)(zw >> ((g & 7) * 4)) & 0xFu;
    const uint32_t hz2u = 0x64006400u | z | (z << 16);
    const uint16_t hs = __builtin_bit_cast(uint16_t, __float2half(sf));
    const uint32_t s2u = (uint32_t)hs | ((uint32_t)hs << 16);

    uint4 dqv[8];
    {
      const uint32_t w[8] = {q0.x, q0.y, q0.z, q0.w, q1.x, q1.y, q1.z, q1.w};
#pragma unroll
      for (int i = 0; i < 8; ++i) dqv[i] = dq_word(w[i], hz2u, s2u);
    }

    if (it > 0) __syncthreads();  // prior MFMA readers done before overwrite

    // word i -> ks = wh*4 + (i>>1), hf = i&1; dst = [(nblk*8+ks)*64 + hf*32 + l31]*8
#pragma unroll
    for (int i = 0; i < 8; ++i) {
      *(uint4*)(bdst0 + (((i >> 1) * 64 + (i & 1) * 32) * 8)) = dqv[i];
    }
    __syncthreads();

    if (it + 1 < NITER) {
      q0 = *(const uint4*)(qweight + qw_base + (it + 1) * 16);
      q1 = *(const uint4*)(qweight + qw_base + (it + 1) * 16 + 4);
    }

    // ---- MFMA phase: 8 k16-steps; A coalesced from global, B from LDS
#pragma unroll
    for (int ks = 0; ks < 8; ++ks) {
      half8 a0, a1;
      if (XF16) {
        const long long k16g = (long long)kslice * 64 + it * 8 + ks;
        a0 = *(const half8*)(aT + (((2LL * mw) * K16S + k16g) * 64 + lane) * 8);
        a1 = *(const half8*)(aT + (((2LL * mw + 1) * K16S + k16g) * 64 + lane) * 8);
      } else {
        const int ko = kbase + it * BK + ks * 16;
        float4 f0 = *(const float4*)(xf32 + arow0 + ko);
        float4 f1 = *(const float4*)(xf32 + arow0 + ko + 4);
        a0 = half8{(_Float16)f0.x, (_Float16)f0.y, (_Float16)f0.z, (_Float16)f0.w,
                   (_Float16)f1.x, (_Float16)f1.y, (_Float16)f1.z, (_Float16)f1.w};
        float4 g0 = *(const float4*)(xf32 + arow1 + ko);
        float4 g1 = *(const float4*)(xf32 + arow1 + ko + 4);
        a1 = half8{(_Float16)g0.x, (_Float16)g0.y, (_Float16)g0.z, (_Float16)g0.w,
                   (_Float16)g1.x, (_Float16)g1.y, (_Float16)g1.z, (_Float16)g1.w};
      }
      const uint16_t* bp = &bT[((nw * 16 + ks) * 64 + lane) * 8];
      half8 b0 = *(const half8*)bp;
      half8 b1 = *(const half8*)(bp + 8 * 64 * 8);  // next nblk
      acc[0][0] = __builtin_amdgcn_mfma_f32_32x32x16_f16(a0, b0, acc[0][0], 0, 0, 0);
      acc[0][1] = __builtin_amdgcn_mfma_f32_32x32x16_f16(a0, b1, acc[0][1], 0, 0, 0);
      acc[1][0] = __builtin_amdgcn_mfma_f32_32x32x16_f16(a1, b0, acc[1][0], 0, 0, 0);
      acc[1][1] = __builtin_amdgcn_mfma_f32_32x32x16_f16(a1, b1, acc[1][1], 0, 0, 0);
    }
  }

  // ---- epilogue: K-split partials into bias-pre-initialized out
  // C/D 32x32: col = lane&31, row = (reg&3) + 8*(reg>>2) + 4*(lane>>5)
  const int cn = n0 + nw * 64 + l31;
#pragma unroll
  for (int im = 0; im < 2; ++im) {
#pragma unroll
    for (int in2 = 0; in2 < 2; ++in2) {
#pragma unroll
      for (int reg = 0; reg < 16; ++reg) {
        int m = mw * 64 + im * 32 + (reg & 3) + 8 * (reg >> 2) + 4 * half;
        atomicAdd(out + (long long)m * OUT_F + cn + in2 * 32, acc[im][in2][reg]);
      }
    }
  }
}

// prologue: out = bias (row-broadcast) and aT = f16(x) in fragment-major order
// aT[mblk][k16][lane][8]: element = x[mblk*32 + (lane&31)][k16*16 + (lane>>5)*8 + j]
__global__ __launch_bounds__(256) void prologue(
    const float* __restrict__ x, const float* __restrict__ bias,
    float* __restrict__ out, uint16_t* __restrict__ aT) {
  const int t = blockIdx.x * 256 + threadIdx.x;
  const int idx = t * 8;
  const int row = idx >> 13;      // / IN_F
  const int col = idx & (IN_F - 1);

  float4 b0 = *(const float4*)(bias + (idx & (OUT_F - 1)));
  float4 b1 = *(const float4*)(bias + ((idx + 4) & (OUT_F - 1)));
  *(float4*)(out + idx) = b0;
  *(float4*)(out + idx + 4) = b1;

  float4 v0 = *(const float4*)(x + idx);
  float4 v1 = *(const float4*)(x + idx + 4);
  union { uint16_t h[8]; uint4 v; } r;
  r.h[0] = __builtin_bit_cast(uint16_t, __float2half(v0.x));
  r.h[1] = __builtin_bit_cast(uint16_t, __float2half(v0.y));
  r.h[2] = __builtin_bit_cast(uint16_t, __float2half(v0.z));
  r.h[3] = __builtin_bit_cast(uint16_t, __float2half(v0.w));
  r.h[4] = __builtin_bit_cast(uint16_t, __float2half(v1.x));
  r.h[5] = __builtin_bit_cast(uint16_t, __float2half(v1.y));
  r.h[6] = __builtin_bit_cast(uint16_t, __float2half(v1.z));
  r.h[7] = __builtin_bit_cast(uint16_t, __float2half(v1.w));

  const int mblk = row >> 5;
  const int l31 = row & 31;
  const int k16 = col >> 4;
  const int hf = (col >> 3) & 1;
  const long long dst = (((long long)mblk * K16S + k16) * 64 + hf * 32 + l31) * 8;
  *(uint4*)(aT + dst) = r.v;
}

__global__ __launch_bounds__(256) void init_out(const float* __restrict__ bias,
                                                float* __restrict__ out) {
  int idx = (blockIdx.x * 256 + threadIdx.x) * 4;
  float4 b = *(const float4*)(bias + (idx & (OUT_F - 1)));
  *(float4*)(out + idx) = b;
}

extern "C" void kernel_launch(void* const* d_in, const int* in_sizes, int n_in,
                              void* d_out, int out_size, void* d_ws, size_t ws_size,
                              hipStream_t stream) {
  const float* x = (const float*)d_in[0];
  const int* qw = (const int*)d_in[1];
  const float* sc = (const float*)d_in[2];
  const int* qz = (const int*)d_in[3];
  const float* bias = (const float*)d_in[4];
  float* out = (float*)d_out;
  uint16_t* aT = (uint16_t*)d_ws;

  const size_t need = (size_t)M_TOTAL * IN_F * sizeof(uint16_t);  // 2 MiB
  if (ws_size >= need) {
    prologue<<<(M_TOTAL * IN_F) / (256 * 8), 256, 0, stream>>>(x, bias, out, aT);
    awq_main<1><<<NTILES * KSPLIT, 256, 0, stream>>>(x, aT, qw, sc, qz, out);
  } else {
    init_out<<<(M_TOTAL * OUT_F) / (256 * 4), 256, 0, stream>>>(bias, out);
    awq_main<0><<<NTILES * KSPLIT, 256, 0, stream>>>(x, aT, qw, sc, qz, out);
  }
}

// Round 7
// 122.448 us; speedup vs baseline: 1.1735x; 1.0597x over previous
//
#include <hip/hip_runtime.h>
#include <hip/hip_fp16.h>
#include <stdint.h>

#define IN_F 8192
#define OUT_F 8192
#define NGROUPS 64
#define QW_COLS 1024   // IN_F/8 packed int32 per output row
#define QZ_COLS 8
#define M_TOTAL 128
#define BN 128
#define BK 128         // == GROUP_SIZE
#define KSPLIT 8
#define KRANGE (IN_F / KSPLIT)  // 1024
#define NITER (KRANGE / BK)     // 8
#define NTILES (OUT_F / BN)     // 64
#define K16S (IN_F / 16)        // 512

typedef _Float16 half8 __attribute__((ext_vector_type(8)));
typedef float floatx16 __attribute__((ext_vector_type(16)));

// Dequant one packed word (8 nibbles) -> 8 f16 in order, bit-identical to ref.
__device__ inline uint4 dq_word(uint32_t w, uint32_t hz2u, uint32_t s2u) {
  const __half2 hz2 = __builtin_bit_cast(__half2, hz2u);
  const __half2 s2 = __builtin_bit_cast(__half2, s2u);
  uint32_t r[4];
#pragma unroll
  for (int p = 0; p < 4; ++p) {
    uint32_t t = ((w >> (4 * p)) & 0x000F000Fu) | 0x64006400u;
    __half2 v = __hmul2(__hsub2(__builtin_bit_cast(__half2, t), hz2), s2);
    r[p] = __builtin_bit_cast(uint32_t, v);  // (elem p, elem p+4)
  }
  uint4 o;
  o.x = (r[0] & 0xFFFFu) | (r[1] << 16);
  o.y = (r[2] & 0xFFFFu) | (r[3] << 16);
  o.z = (r[0] >> 16) | (r[1] & 0xFFFF0000u);
  o.w = (r[2] >> 16) | (r[3] & 0xFFFF0000u);
  return o;
}

// dequant 8 words of one column-group and scatter into a B fragment buffer
__device__ inline void dq_to_lds(uint4 q0, uint4 q1, float sf, uint32_t z,
                                 uint16_t* bdst0) {
  const uint32_t hz2u = 0x64006400u | z | (z << 16);
  const uint16_t hs = __builtin_bit_cast(uint16_t, __float2half(sf));
  const uint32_t s2u = (uint32_t)hs | ((uint32_t)hs << 16);
  const uint32_t w[8] = {q0.x, q0.y, q0.z, q0.w, q1.x, q1.y, q1.z, q1.w};
#pragma unroll
  for (int i = 0; i < 8; ++i) {
    uint4 v = dq_word(w[i], hz2u, s2u);
    *(uint4*)(bdst0 + (((i >> 1) * 64 + (i & 1) * 32) * 8)) = v;
  }
}

// Fast path: A from fragment-major f16 (ws), fully software-pipelined.
__global__ __launch_bounds__(256, 2) void awq_fast(
    const uint16_t* __restrict__ aT, const int* __restrict__ qweight,
    const float* __restrict__ scales, const int* __restrict__ qzeros,
    float* __restrict__ out) {
  __shared__ uint16_t bT[2][BN * BK];  // 2 x 32 KiB, fragment-major

  const int tid = threadIdx.x;
  const int bx = blockIdx.x;
  const int ntile = bx & (NTILES - 1);
  const int kslice = bx >> 6;
  const int n0 = ntile * BN;
  const int kbase = kslice * KRANGE;

  const int lane = tid & 63;
  const int wave = tid >> 6;
  const int mw = wave >> 1;   // 2x2 waves; wave tile 64x64
  const int nw = wave & 1;
  const int l31 = lane & 31;
  const int half = lane >> 5;

  floatx16 acc[2][2] = {};

  // dequant map: thread -> (col = tid>>1, k-half = tid&1), 8 words/iter
  const int wcol = tid >> 1;
  const int wh = tid & 1;
  const long long qw_base = (long long)(n0 + wcol) * QW_COLS + (kbase >> 3) + wh * 8;
  const long long sc_base = (long long)(n0 + wcol) * NGROUPS;
  const long long qz_base = (long long)(n0 + wcol) * QZ_COLS;
  const int bdst_off = (((wcol >> 5) * 8 + wh * 4) * 64 + (wcol & 31)) * 8;

  // qword double slots: slot p holds qw[iter] with iter&1==p, 2 ahead
  uint4 q0s[2], q1s[2];
  q0s[0] = *(const uint4*)(qweight + qw_base);
  q1s[0] = *(const uint4*)(qweight + qw_base + 4);
  q0s[1] = *(const uint4*)(qweight + qw_base + 16);
  q1s[1] = *(const uint4*)(qweight + qw_base + 20);

  // A fragment double buffer: aF[parity][im][ks]
  half8 aF[2][2][8];
#pragma unroll
  for (int ks = 0; ks < 8; ++ks)
#pragma unroll
    for (int im = 0; im < 2; ++im) {
      const long long k16g = (long long)kslice * 64 + ks;
      aF[0][im][ks] =
          *(const half8*)(aT + (((2LL * mw + im) * K16S + k16g) * 64 + lane) * 8);
    }

  // pre-loop: dequant qw[0] into buf 0 (visible after loop-top sync)
  {
    const int g = kslice * NITER;
    const float sf = scales[sc_base + g];
    const int zw = qzeros[qz_base + (g >> 3)];
    const uint32_t z = (uint32_t)(zw >> ((g & 7) * 4)) & 0xFu;
    dq_to_lds(q0s[0], q1s[0], sf, z, &bT[0][bdst_off]);
  }

#pragma unroll
  for (int it = 0; it < NITER; ++it) {
    const int pc = it & 1;
    const int pn = pc ^ 1;
    __syncthreads();  // buf[pc] writes visible; buf[pn] readers (it-1) done

    // prefetch qw[it+2] into the slot freed by qw[it]
    if (it + 2 < NITER) {
      q0s[pc] = *(const uint4*)(qweight + qw_base + (it + 2) * 16);
      q1s[pc] = *(const uint4*)(qweight + qw_base + (it + 2) * 16 + 4);
    }
    // prefetch A fragments for it+1 (consumed one full iteration later)
    if (it + 1 < NITER) {
#pragma unroll
      for (int ks = 0; ks < 8; ++ks)
#pragma unroll
        for (int im = 0; im < 2; ++im) {
          const long long k16g = (long long)kslice * 64 + (it + 1) * 8 + ks;
          aF[pn][im][ks] =
              *(const half8*)(aT + (((2LL * mw + im) * K16S + k16g) * 64 + lane) * 8);
        }
    }

    // MFMA phase on buf[pc] / aF[pc]
#pragma unroll
    for (int ks = 0; ks < 8; ++ks) {
      const uint16_t* bp = &bT[pc][((nw * 16 + ks) * 64 + lane) * 8];
      half8 b0 = *(const half8*)bp;
      half8 b1 = *(const half8*)(bp + 8 * 64 * 8);
      acc[0][0] = __builtin_amdgcn_mfma_f32_32x32x16_f16(aF[pc][0][ks], b0, acc[0][0], 0, 0, 0);
      acc[0][1] = __builtin_amdgcn_mfma_f32_32x32x16_f16(aF[pc][0][ks], b1, acc[0][1], 0, 0, 0);
      acc[1][0] = __builtin_amdgcn_mfma_f32_32x32x16_f16(aF[pc][1][ks], b0, acc[1][0], 0, 0, 0);
      acc[1][1] = __builtin_amdgcn_mfma_f32_32x32x16_f16(aF[pc][1][ks], b1, acc[1][1], 0, 0, 0);
    }

    // dequant qw[it+1] -> buf[pn] (VALU/DS co-issues with MFMA drain)
    if (it + 1 < NITER) {
      const int g = kslice * NITER + it + 1;
      const float sf = scales[sc_base + g];
      const int zw = qzeros[qz_base + (g >> 3)];
      const uint32_t z = (uint32_t)(zw >> ((g & 7) * 4)) & 0xFu;
      dq_to_lds(q0s[pn], q1s[pn], sf, z, &bT[pn][bdst_off]);
    }
  }

  // epilogue: K-split partials into bias-pre-initialized out
  // C/D 32x32: col = lane&31, row = (reg&3) + 8*(reg>>2) + 4*(lane>>5)
  const int cn = n0 + nw * 64 + l31;
#pragma unroll
  for (int im = 0; im < 2; ++im)
#pragma unroll
    for (int in2 = 0; in2 < 2; ++in2)
#pragma unroll
      for (int reg = 0; reg < 16; ++reg) {
        int m = mw * 64 + im * 32 + (reg & 3) + 8 * (reg >> 2) + 4 * half;
        atomicAdd(out + (long long)m * OUT_F + cn + in2 * 32, acc[im][in2][reg]);
      }
}

// Fallback (ws too small): round-6 structure, f32 x reads. Correct, slower.
__global__ __launch_bounds__(256) void awq_fallback(
    const float* __restrict__ xf32, const int* __restrict__ qweight,
    const float* __restrict__ scales, const int* __restrict__ qzeros,
    float* __restrict__ out) {
  __shared__ uint16_t bT[BN * BK];

  const int tid = threadIdx.x;
  const int bx = blockIdx.x;
  const int ntile = bx & (NTILES - 1);
  const int kslice = bx >> 6;
  const int n0 = ntile * BN;
  const int kbase = kslice * KRANGE;

  const int lane = tid & 63;
  const int wave = tid >> 6;
  const int mw = wave >> 1;
  const int nw = wave & 1;
  const int l31 = lane & 31;
  const int half = lane >> 5;

  floatx16 acc[2][2] = {};

  const int wcol = tid >> 1;
  const int wh = tid & 1;
  const long long qw_base = (long long)(n0 + wcol) * QW_COLS + (kbase >> 3) + wh * 8;
  const long long sc_base = (long long)(n0 + wcol) * NGROUPS;
  const long long qz_base = (long long)(n0 + wcol) * QZ_COLS;
  const int bdst_off = (((wcol >> 5) * 8 + wh * 4) * 64 + (wcol & 31)) * 8;

  const long long arow0 = (long long)(mw * 64 + l31) * IN_F + half * 8;
  const long long arow1 = (long long)(mw * 64 + 32 + l31) * IN_F + half * 8;

  for (int it = 0; it < NITER; ++it) {
    const int g = kslice * NITER + it;
    const float sf = scales[sc_base + g];
    const int zw = qzeros[qz_base + (g >> 3)];
    const uint32_t z = (uint32_t)(zw >> ((g & 7) * 4)) & 0xFu;
    uint4 q0 = *(const uint4*)(qweight + qw_base + it * 16);
    uint4 q1 = *(const uint4*)(qweight + qw_base + it * 16 + 4);

    if (it > 0) __syncthreads();
    dq_to_lds(q0, q1, sf, z, &bT[bdst_off]);
    __syncthreads();

#pragma unroll
    for (int ks = 0; ks < 8; ++ks) {
      const int ko = kbase + it * BK + ks * 16;
      float4 f0 = *(const float4*)(xf32 + arow0 + ko);
      float4 f1 = *(const float4*)(xf32 + arow0 + ko + 4);
      half8 a0 = half8{(_Float16)f0.x, (_Float16)f0.y, (_Float16)f0.z, (_Float16)f0.w,
                       (_Float16)f1.x, (_Float16)f1.y, (_Float16)f1.z, (_Float16)f1.w};
      float4 g0 = *(const float4*)(xf32 + arow1 + ko);
      float4 g1 = *(const float4*)(xf32 + arow1 + ko + 4);
      half8 a1 = half8{(_Float16)g0.x, (_Float16)g0.y, (_Float16)g0.z, (_Float16)g0.w,
                       (_Float16)g1.x, (_Float16)g1.y, (_Float16)g1.z, (_Float16)g1.w};
      const uint16_t* bp = &bT[((nw * 16 + ks) * 64 + lane) * 8];
      half8 b0 = *(const half8*)bp;
      half8 b1 = *(const half8*)(bp + 8 * 64 * 8);
      acc[0][0] = __builtin_amdgcn_mfma_f32_32x32x16_f16(a0, b0, acc[0][0], 0, 0, 0);
      acc[0][1] = __builtin_amdgcn_mfma_f32_32x32x16_f16(a0, b1, acc[0][1], 0, 0, 0);
      acc[1][0] = __builtin_amdgcn_mfma_f32_32x32x16_f16(a1, b0, acc[1][0], 0, 0, 0);
      acc[1][1] = __builtin_amdgcn_mfma_f32_32x32x16_f16(a1, b1, acc[1][1], 0, 0, 0);
    }
  }

  const int cn = n0 + nw * 64 + l31;
#pragma unroll
  for (int im = 0; im < 2; ++im)
#pragma unroll
    for (int in2 = 0; in2 < 2; ++in2)
#pragma unroll
      for (int reg = 0; reg < 16; ++reg) {
        int m = mw * 64 + im * 32 + (reg & 3) + 8 * (reg >> 2) + 4 * half;
        atomicAdd(out + (long long)m * OUT_F + cn + in2 * 32, acc[im][in2][reg]);
      }
}

// prologue: out = bias (row-broadcast) and aT = f16(x) fragment-major:
// aT[mblk][k16][lane][8] = x[mblk*32 + (lane&31)][k16*16 + (lane>>5)*8 + j]
__global__ __launch_bounds__(256) void prologue(
    const float* __restrict__ x, const float* __restrict__ bias,
    float* __restrict__ out, uint16_t* __restrict__ aT) {
  const int t = blockIdx.x * 256 + threadIdx.x;
  const int idx = t * 8;
  const int row = idx >> 13;
  const int col = idx & (IN_F - 1);

  float4 b0 = *(const float4*)(bias + (idx & (OUT_F - 1)));
  float4 b1 = *(const float4*)(bias + ((idx + 4) & (OUT_F - 1)));
  *(float4*)(out + idx) = b0;
  *(float4*)(out + idx + 4) = b1;

  float4 v0 = *(const float4*)(x + idx);
  float4 v1 = *(const float4*)(x + idx + 4);
  union { uint16_t h[8]; uint4 v; } r;
  r.h[0] = __builtin_bit_cast(uint16_t, __float2half(v0.x));
  r.h[1] = __builtin_bit_cast(uint16_t, __float2half(v0.y));
  r.h[2] = __builtin_bit_cast(uint16_t, __float2half(v0.z));
  r.h[3] = __builtin_bit_cast(uint16_t, __float2half(v0.w));
  r.h[4] = __builtin_bit_cast(uint16_t, __float2half(v1.x));
  r.h[5] = __builtin_bit_cast(uint16_t, __float2half(v1.y));
  r.h[6] = __builtin_bit_cast(uint16_t, __float2half(v1.z));
  r.h[7] = __builtin_bit_cast(uint16_t, __float2half(v1.w));

  const int mblk = row >> 5;
  const int l31r = row & 31;
  const int k16 = col >> 4;
  const int hf = (col >> 3) & 1;
  const long long dst = (((long long)mblk * K16S + k16) * 64 + hf * 32 + l31r) * 8;
  *(uint4*)(aT + dst) = r.v;
}

__global__ __launch_bounds__(256) void init_out(const float* __restrict__ bias,
                                                float* __restrict__ out) {
  int idx = (blockIdx.x * 256 + threadIdx.x) * 4;
  float4 b = *(const float4*)(bias + (idx & (OUT_F - 1)));
  *(float4*)(out + idx) = b;
}

extern "C" void kernel_launch(void* const* d_in, const int* in_sizes, int n_in,
                              void* d_out, int out_size, void* d_ws, size_t ws_size,
                              hipStream_t stream) {
  const float* x = (const float*)d_in[0];
  const int* qw = (const int*)d_in[1];
  const float* sc = (const float*)d_in[2];
  const int* qz = (const int*)d_in[3];
  const float* bias = (const float*)d_in[4];
  float* out = (float*)d_out;
  uint16_t* aT = (uint16_t*)d_ws;

  const size_t need = (size_t)M_TOTAL * IN_F * sizeof(uint16_t);  // 2 MiB
  if (ws_size >= need) {
    prologue<<<(M_TOTAL * IN_F) / (256 * 8), 256, 0, stream>>>(x, bias, out, aT);
    awq_fast<<<NTILES * KSPLIT, 256, 0, stream>>>(aT, qw, sc, qz, out);
  } else {
    init_out<<<(M_TOTAL * OUT_F) / (256 * 4), 256, 0, stream>>>(bias, out);
    awq_fallback<<<NTILES * KSPLIT, 256, 0, stream>>>(x, qw, sc, qz, out);
  }
}

// Round 8
// 112.650 us; speedup vs baseline: 1.2755x; 1.0870x over previous
//
#include <hip/hip_runtime.h>
#include <hip/hip_fp16.h>
#include <stdint.h>

#define IN_F 8192
#define OUT_F 8192
#define NGROUPS 64
#define QW_COLS 1024   // IN_F/8 packed int32 per output row
#define QZ_COLS 8
#define M_TOTAL 128
#define BN 128
#define KSPLIT 8
#define KRANGE (IN_F / KSPLIT)  // 1024
#define BK 64
#define NITER (KRANGE / BK)     // 16
#define NTILES (OUT_F / BN)     // 64
#define K16S (IN_F / 16)        // 512

typedef _Float16 half8 __attribute__((ext_vector_type(8)));
typedef float floatx16 __attribute__((ext_vector_type(16)));

typedef __attribute__((address_space(3))) uint32_t* lds_u32p;
typedef const __attribute__((address_space(1))) uint32_t* glb_u32p;

// async 16B/lane global->LDS; LDS dest = uniform base + lane*16
__device__ inline void gl_lds16(const uint16_t* g, uint16_t* l) {
  __builtin_amdgcn_global_load_lds((glb_u32p)g, (lds_u32p)l, 16, 0, 0);
}

// Dequant one packed word (8 nibbles) -> 8 f16 in k-order, bit-identical to ref.
__device__ inline uint4 dq_word(uint32_t w, uint32_t hz2u, uint32_t s2u) {
  const __half2 hz2 = __builtin_bit_cast(__half2, hz2u);
  const __half2 s2 = __builtin_bit_cast(__half2, s2u);
  uint32_t r[4];
#pragma unroll
  for (int p = 0; p < 4; ++p) {
    uint32_t t = ((w >> (4 * p)) & 0x000F000Fu) | 0x64006400u;
    __half2 v = __hmul2(__hsub2(__builtin_bit_cast(__half2, t), hz2), s2);
    r[p] = __builtin_bit_cast(uint32_t, v);  // (elem p, elem p+4)
  }
  uint4 o;
  o.x = (r[0] & 0xFFFFu) | (r[1] << 16);
  o.y = (r[2] & 0xFFFFu) | (r[3] << 16);
  o.z = (r[0] >> 16) | (r[1] & 0xFFFF0000u);
  o.w = (r[2] >> 16) | (r[3] & 0xFFFF0000u);
  return o;
}

// dequant this thread's 4 words (k-span 32 of BK=64) into B fragment buffer
__device__ inline void dq4_to_lds(uint4 q, float sf, uint32_t z, uint16_t* bbuf,
                                  int bOff, int wh) {
  const uint32_t hz2u = 0x64006400u | z | (z << 16);
  const uint16_t hs = __builtin_bit_cast(uint16_t, __float2half(sf));
  const uint32_t s2u = (uint32_t)hs | ((uint32_t)hs << 16);
  const uint32_t w[4] = {q.x, q.y, q.z, q.w};
#pragma unroll
  for (int i = 0; i < 4; ++i) {
    uint4 v = dq_word(w[i], hz2u, s2u);
    // word w_local = wh*4+i -> ks = wh*2 + (i>>1), hf = i&1
    *(uint4*)(bbuf + bOff + (((wh * 2 + (i >> 1)) * 64 + (i & 1) * 32) * 8)) = v;
  }
}

// EPI 0: plain stores to per-kslice partial buffer (reduce kernel finishes).
// EPI 1: atomicAdd into bias-pre-initialized out (mid path, no partial buffer).
template <int EPI>
__global__ __launch_bounds__(256, 2) void awq_fast(
    const uint16_t* __restrict__ aT, const int* __restrict__ qweight,
    const float* __restrict__ scales, const int* __restrict__ qzeros,
    float* __restrict__ part, float* __restrict__ out) {
  // fragment-major double buffers: chunk (blk, k16) -> 64 lanes x 8 halves
  __shared__ uint16_t aL[2][4 * 4 * 64 * 8];  // 2 x 16 KiB
  __shared__ uint16_t bL[2][4 * 4 * 64 * 8];  // 2 x 16 KiB

  const int tid = threadIdx.x;
  const int bx = blockIdx.x;
  const int ntile = bx & (NTILES - 1);
  const int kslice = bx >> 6;
  const int n0 = ntile * BN;
  const int kbase = kslice * KRANGE;

  const int lane = tid & 63;
  const int wave = tid >> 6;
  const int mw = wave >> 1;  // wave tile 64x64: mblk {2mw,2mw+1} x nblk {2nw,2nw+1}
  const int nw = wave & 1;
  const int l31 = lane & 31;
  const int half = lane >> 5;

  floatx16 acc[2][2] = {};

  // ---- per-thread dequant role: col = tid>>1 (128 cols), wh = tid&1
  const int wcol = tid >> 1;
  const int wh = tid & 1;
  const long long wbase = (long long)(n0 + wcol) * QW_COLS + (kbase >> 3) + wh * 4;
  const int bOff = ((wcol >> 5) * 4 * 64 + (wcol & 31)) * 8;

  // preload this kslice's 8 scales + the single qzeros word for this col
  const float4 sA = *(const float4*)(scales + (long long)(n0 + wcol) * NGROUPS + kslice * 8);
  const float4 sB = *(const float4*)(scales + (long long)(n0 + wcol) * NGROUPS + kslice * 8 + 4);
  const float sarr[8] = {sA.x, sA.y, sA.z, sA.w, sB.x, sB.y, sB.z, sB.w};
  const uint32_t zword = (uint32_t)qzeros[(long long)(n0 + wcol) * QZ_COLS + kslice];

  // qweight register pipeline: q[j] = 4 words for dequant-iteration j
  uint4 q0 = *(const uint4*)(qweight + wbase);       // q[0]
  uint4 qs[2];
  qs[1] = *(const uint4*)(qweight + wbase + 8);      // q[1]
  qs[0] = *(const uint4*)(qweight + wbase + 16);     // q[2]

  // ---- pre-loop: stage A(it=0) + dequant q[0] into buf 0
  {
    const uint16_t* gb = aT + (((long long)wave * K16S + kslice * 64) * 64 + lane) * 8;
#pragma unroll
    for (int i = 0; i < 4; ++i)
      gl_lds16(gb + (long long)i * 512, &aL[0][(wave * 4 + i) * 512]);
    dq4_to_lds(q0, sarr[0], zword & 0xFu, bL[0], bOff, wh);
  }

#pragma unroll
  for (int it = 0; it < NITER; ++it) {
    const int pb = it & 1;
    const int pn = pb ^ 1;
    __syncthreads();  // drains buf[pb] A-loads (vmcnt) + B ds_writes (lgkm)

    if (it + 1 < NITER) {
      // async A-stage for it+1 -> buf pn (flies under this iter's MFMA)
      const uint16_t* gb =
          aT + (((long long)wave * K16S + kslice * 64 + (it + 1) * 4) * 64 + lane) * 8;
#pragma unroll
      for (int i = 0; i < 4; ++i)
        gl_lds16(gb + (long long)i * 512, &aL[pn][(wave * 4 + i) * 512]);
      // dequant q[it+1] -> buf pn
      const int gl = (it + 1) >> 1;
      const uint32_t z = (zword >> (gl * 4)) & 0xFu;
      dq4_to_lds(qs[(it + 1) & 1], sarr[gl], z, bL[pn], bOff, wh);
      // refill the consumed slot with q[it+3]
      if (it + 3 < NITER)
        qs[(it + 1) & 1] = *(const uint4*)(qweight + wbase + (it + 3) * 8);
    }

    // ---- MFMA phase on buf pb: 4 k16-steps x (2 mblk x 2 nblk)
#pragma unroll
    for (int ks = 0; ks < 4; ++ks) {
      half8 a0 = *(const half8*)(&aL[pb][((2 * mw) * 4 + ks) * 512 + lane * 8]);
      half8 a1 = *(const half8*)(&aL[pb][((2 * mw + 1) * 4 + ks) * 512 + lane * 8]);
      half8 b0 = *(const half8*)(&bL[pb][((2 * nw) * 4 + ks) * 512 + lane * 8]);
      half8 b1 = *(const half8*)(&bL[pb][((2 * nw + 1) * 4 + ks) * 512 + lane * 8]);
      acc[0][0] = __builtin_amdgcn_mfma_f32_32x32x16_f16(a0, b0, acc[0][0], 0, 0, 0);
      acc[0][1] = __builtin_amdgcn_mfma_f32_32x32x16_f16(a0, b1, acc[0][1], 0, 0, 0);
      acc[1][0] = __builtin_amdgcn_mfma_f32_32x32x16_f16(a1, b0, acc[1][0], 0, 0, 0);
      acc[1][1] = __builtin_amdgcn_mfma_f32_32x32x16_f16(a1, b1, acc[1][1], 0, 0, 0);
    }
  }

  // ---- epilogue. C/D 32x32: col=lane&31, row=(reg&3)+8*(reg>>2)+4*(lane>>5)
#pragma unroll
  for (int im = 0; im < 2; ++im)
#pragma unroll
    for (int in2 = 0; in2 < 2; ++in2) {
      const int n = n0 + (2 * nw + in2) * 32 + l31;
#pragma unroll
      for (int reg = 0; reg < 16; ++reg) {
        const int m = (2 * mw + im) * 32 + (reg & 3) + 8 * (reg >> 2) + 4 * half;
        if (EPI == 0) {
          part[((long long)kslice * M_TOTAL + m) * OUT_F + n] = acc[im][in2][reg];
        } else {
          atomicAdd(out + (long long)m * OUT_F + n, acc[im][in2][reg]);
        }
      }
    }
}

// reduce: out = bias + sum over KSPLIT partials
__global__ __launch_bounds__(256) void reduce_out(const float* __restrict__ part,
                                                  const float* __restrict__ bias,
                                                  float* __restrict__ out) {
  const long long idx = ((long long)blockIdx.x * 256 + threadIdx.x) * 4;
  float4 s = *(const float4*)(bias + (idx & (OUT_F - 1)));
#pragma unroll
  for (int k = 0; k < KSPLIT; ++k) {
    float4 p = *(const float4*)(part + (long long)k * M_TOTAL * OUT_F + idx);
    s.x += p.x; s.y += p.y; s.z += p.z; s.w += p.w;
  }
  *(float4*)(out + idx) = s;
}

// prologue: aT = f16(x) fragment-major:
// aT[mblk][k16][hf*32+l31][j] = x[mblk*32 + l31][k16*16 + hf*8 + j]
__global__ __launch_bounds__(256) void prologue(const float* __restrict__ x,
                                                uint16_t* __restrict__ aT) {
  const int t = blockIdx.x * 256 + threadIdx.x;
  const int idx = t * 8;
  const int row = idx >> 13;
  const int col = idx & (IN_F - 1);

  float4 v0 = *(const float4*)(x + idx);
  float4 v1 = *(const float4*)(x + idx + 4);
  union { uint16_t h[8]; uint4 v; } r;
  r.h[0] = __builtin_bit_cast(uint16_t, __float2half(v0.x));
  r.h[1] = __builtin_bit_cast(uint16_t, __float2half(v0.y));
  r.h[2] = __builtin_bit_cast(uint16_t, __float2half(v0.z));
  r.h[3] = __builtin_bit_cast(uint16_t, __float2half(v0.w));
  r.h[4] = __builtin_bit_cast(uint16_t, __float2half(v1.x));
  r.h[5] = __builtin_bit_cast(uint16_t, __float2half(v1.y));
  r.h[6] = __builtin_bit_cast(uint16_t, __float2half(v1.z));
  r.h[7] = __builtin_bit_cast(uint16_t, __float2half(v1.w));

  const int mblk = row >> 5;
  const int l31r = row & 31;
  const int k16 = col >> 4;
  const int hf = (col >> 3) & 1;
  const long long dst = (((long long)mblk * K16S + k16) * 64 + hf * 32 + l31r) * 8;
  *(uint4*)(aT + dst) = r.v;
}

__global__ __launch_bounds__(256) void init_out(const float* __restrict__ bias,
                                                float* __restrict__ out) {
  int idx = (blockIdx.x * 256 + threadIdx.x) * 4;
  float4 b = *(const float4*)(bias + (idx & (OUT_F - 1)));
  *(float4*)(out + idx) = b;
}

// low fallback: no workspace needed; f32 x reads, atomics (round-6 lineage)
__global__ __launch_bounds__(256) void awq_fallback(
    const float* __restrict__ xf32, const int* __restrict__ qweight,
    const float* __restrict__ scales, const int* __restrict__ qzeros,
    float* __restrict__ out) {
  __shared__ uint16_t bT[4 * 4 * 64 * 8 * 2];  // 32 KiB single buffer (BK=128 here)

  const int tid = threadIdx.x;
  const int bx = blockIdx.x;
  const int ntile = bx & (NTILES - 1);
  const int kslice = bx >> 6;
  const int n0 = ntile * BN;
  const int kbase = kslice * KRANGE;

  const int lane = tid & 63;
  const int wave = tid >> 6;
  const int mw = wave >> 1;
  const int nw = wave & 1;
  const int l31 = lane & 31;
  const int half = lane >> 5;

  floatx16 acc[2][2] = {};

  const int wcol = tid >> 1;
  const int wh = tid & 1;
  const long long qw_base = (long long)(n0 + wcol) * QW_COLS + (kbase >> 3) + wh * 8;
  const long long sc_base = (long long)(n0 + wcol) * NGROUPS;
  const long long qz_base = (long long)(n0 + wcol) * QZ_COLS;
  const int bOff = ((wcol >> 5) * 8 * 64 + (wcol & 31)) * 8;

  const long long arow0 = (long long)(mw * 64 + l31) * IN_F + half * 8;
  const long long arow1 = (long long)(mw * 64 + 32 + l31) * IN_F + half * 8;

  for (int it = 0; it < NITER / 2; ++it) {  // BK=128 here
    const int g = kslice * 8 + it;
    const float sf = scales[sc_base + g];
    const int zw = qzeros[qz_base + (g >> 3)];
    const uint32_t z = (uint32_t)(zw >> ((g & 7) * 4)) & 0xFu;
    const uint32_t hz2u = 0x64006400u | z | (z << 16);
    const uint16_t hs = __builtin_bit_cast(uint16_t, __float2half(sf));
    const uint32_t s2u = (uint32_t)hs | ((uint32_t)hs << 16);
    uint4 q0 = *(const uint4*)(qweight + qw_base + it * 16);
    uint4 q1 = *(const uint4*)(qweight + qw_base + it * 16 + 4);

    if (it > 0) __syncthreads();
    const uint32_t w[8] = {q0.x, q0.y, q0.z, q0.w, q1.x, q1.y, q1.z, q1.w};
#pragma unroll
    for (int i = 0; i < 8; ++i) {
      uint4 v = dq_word(w[i], hz2u, s2u);
      *(uint4*)(&bT[bOff + (((wh * 4 + (i >> 1)) * 64 + (i & 1) * 32) * 8)]) = v;
    }
    __syncthreads();

#pragma unroll
    for (int ks = 0; ks < 8; ++ks) {
      const int ko = kbase + it * 128 + ks * 16;
      float4 f0 = *(const float4*)(xf32 + arow0 + ko);
      float4 f1 = *(const float4*)(xf32 + arow0 + ko + 4);
      half8 a0 = half8{(_Float16)f0.x, (_Float16)f0.y, (_Float16)f0.z, (_Float16)f0.w,
                       (_Float16)f1.x, (_Float16)f1.y, (_Float16)f1.z, (_Float16)f1.w};
      float4 g0 = *(const float4*)(xf32 + arow1 + ko);
      float4 g1 = *(const float4*)(xf32 + arow1 + ko + 4);
      half8 a1 = half8{(_Float16)g0.x, (_Float16)g0.y, (_Float16)g0.z, (_Float16)g0.w,
                       (_Float16)g1.x, (_Float16)g1.y, (_Float16)g1.z, (_Float16)g1.w};
      half8 b0 = *(const half8*)(&bT[((nw * 2) * 8 * 64 + ks * 64 + lane) * 8]);
      half8 b1 = *(const half8*)(&bT[((nw * 2 + 1) * 8 * 64 + ks * 64 + lane) * 8]);
      acc[0][0] = __builtin_amdgcn_mfma_f32_32x32x16_f16(a0, b0, acc[0][0], 0, 0, 0);
      acc[0][1] = __builtin_amdgcn_mfma_f32_32x32x16_f16(a0, b1, acc[0][1], 0, 0, 0);
      acc[1][0] = __builtin_amdgcn_mfma_f32_32x32x16_f16(a1, b0, acc[1][0], 0, 0, 0);
      acc[1][1] = __builtin_amdgcn_mfma_f32_32x32x16_f16(a1, b1, acc[1][1], 0, 0, 0);
    }
  }

  const int cn = n0 + nw * 64 + l31;
#pragma unroll
  for (int im = 0; im < 2; ++im)
#pragma unroll
    for (int in2 = 0; in2 < 2; ++in2)
#pragma unroll
      for (int reg = 0; reg < 16; ++reg) {
        int m = mw * 64 + im * 32 + (reg & 3) + 8 * (reg >> 2) + 4 * half;
        atomicAdd(out + (long long)m * OUT_F + cn + in2 * 32, acc[im][in2][reg]);
      }
}

extern "C" void kernel_launch(void* const* d_in, const int* in_sizes, int n_in,
                              void* d_out, int out_size, void* d_ws, size_t ws_size,
                              hipStream_t stream) {
  const float* x = (const float*)d_in[0];
  const int* qw = (const int*)d_in[1];
  const float* sc = (const float*)d_in[2];
  const int* qz = (const int*)d_in[3];
  const float* bias = (const float*)d_in[4];
  float* out = (float*)d_out;

  const size_t aT_bytes = (size_t)M_TOTAL * IN_F * sizeof(uint16_t);          // 2 MiB
  const size_t part_bytes = (size_t)KSPLIT * M_TOTAL * OUT_F * sizeof(float); // 32 MiB
  uint16_t* aT = (uint16_t*)d_ws;
  float* part = (float*)((char*)d_ws + aT_bytes);

  if (ws_size >= aT_bytes + part_bytes) {
    prologue<<<(M_TOTAL * IN_F) / (256 * 8), 256, 0, stream>>>(x, aT);
    awq_fast<0><<<NTILES * KSPLIT, 256, 0, stream>>>(aT, qw, sc, qz, part, out);
    reduce_out<<<(M_TOTAL * OUT_F) / (256 * 4), 256, 0, stream>>>(part, bias, out);
  } else if (ws_size >= aT_bytes) {
    init_out<<<(M_TOTAL * OUT_F) / (256 * 4), 256, 0, stream>>>(bias, out);
    prologue<<<(M_TOTAL * IN_F) / (256 * 8), 256, 0, stream>>>(x, aT);
    awq_fast<1><<<NTILES * KSPLIT, 256, 0, stream>>>(aT, qw, sc, qz, nullptr, out);
  } else {
    init_out<<<(M_TOTAL * OUT_F) / (256 * 4), 256, 0, stream>>>(bias, out);
    awq_fallback<<<NTILES * KSPLIT, 256, 0, stream>>>(x, qw, sc, qz, out);
  }
}